// Round 12
// baseline (210.793 us; speedup 1.0000x reference)
//
#include <hip/hip_runtime.h>

// Problem constants
#define N_TOK 8192
#define N_EXP 8
#define DIM   2048
#define HID   2048

typedef __attribute__((ext_vector_type(8))) short short8;
typedef __attribute__((ext_vector_type(4))) float f32x4;

__device__ inline unsigned short f2bf(float f) {
  unsigned int u = __builtin_bit_cast(unsigned int, f);
  unsigned int r = u + 0x7FFFu + ((u >> 16) & 1u);   // round-to-nearest-even
  return (unsigned short)(r >> 16);
}

// ---------------------------------------------------------------------------
// Kernel 1: stable counting sort by expert id + compact job list.
// perm[p] = source row; offs[e..e+1] = bounds; jobs[0]=n_bands (256-row),
// jobs[1+j] = e | (mt<<8).
// ---------------------------------------------------------------------------
__global__ __launch_bounds__(256) void sort_experts(const int* __restrict__ idx,
                                                    int* __restrict__ perm,
                                                    int* __restrict__ offs,
                                                    int* __restrict__ jobs) {
  __shared__ int cnt[256][8];
  __shared__ int base[8];
  const int t = threadIdx.x;
  int local[8] = {0,0,0,0,0,0,0,0};
  const int r0 = t * 32;
  for (int i = 0; i < 32; ++i) {
    int e = idx[r0 + i] & 7;
    ++local[e];
  }
#pragma unroll
  for (int e = 0; e < 8; ++e) cnt[t][e] = local[e];
  __syncthreads();
  if (t < 8) {
    int s = 0;
    for (int i = 0; i < 256; ++i) { int v = cnt[i][t]; cnt[i][t] = s; s += v; }
    base[t] = s;
  }
  __syncthreads();
  if (t == 0) {
    int s = 0, njm = 0;
    for (int e = 0; e < 8; ++e) {
      int v = base[e];
      offs[e] = s; base[e] = s; s += v;
      int nm = (v + 255) >> 8;
      for (int mt = 0; mt < nm; ++mt) jobs[1 + njm++] = e | (mt << 8);
    }
    offs[8] = s;
    jobs[0] = njm;
  }
  __syncthreads();
  int pos[8];
#pragma unroll
  for (int e = 0; e < 8; ++e) pos[e] = base[e] + cnt[t][e];
  for (int i = 0; i < 32; ++i) {
    int r = r0 + i;
    int e = idx[r] & 7;
    perm[pos[e]++] = r;
  }
}

// ---------------------------------------------------------------------------
// Kernel 2: gather rows into sorted order + fp32 -> bf16 (x only; no W prep).
// ---------------------------------------------------------------------------
__global__ __launch_bounds__(256) void prep_x(const float* __restrict__ x,
                                              const int* __restrict__ perm,
                                              unsigned short* __restrict__ xs) {
  int gid = blockIdx.x * 256 + threadIdx.x;
  int p = gid >> 8;
  int c = gid & 255;
  int src = perm[p];
  const float* sp = x + (size_t)src * DIM + c * 8;
  float4 a = *(const float4*)sp;
  float4 b = *(const float4*)(sp + 4);
  short8 o;
  o[0] = (short)f2bf(a.x); o[1] = (short)f2bf(a.y);
  o[2] = (short)f2bf(a.z); o[3] = (short)f2bf(a.w);
  o[4] = (short)f2bf(b.x); o[5] = (short)f2bf(b.y);
  o[6] = (short)f2bf(b.z); o[7] = (short)f2bf(b.w);
  *(short8*)(xs + (size_t)p * DIM + c * 8) = o;
}

// ---------------------------------------------------------------------------
// Kernel 3: grouped GEMM, FUSED B-CONVERSION. 256 persistent blocks x 512 thr
// (8 waves, 4M x 2N, per-wave 64x64). Job = 256(M) x 128(N), BK=64, 2 LDS
// slots (96 KiB). A: gload_lds from bf16 xs (4/thread, swizzled source).
// B: fp32 W loaded to regs (16 dword/thread, one column h, coalesced rows),
// RNE-cvt in-register, 2 swizzled ds_write_b128 -> same LDS layout the reads
// use. B regs double-banked (unroll-2), loads 1 tile ahead; vmcnt(16)
// counted wait covers A; lgkmcnt(0) before end barrier covers B writes.
// ---------------------------------------------------------------------------
#define NKT 32           // K-tiles of 64
#define SLOT 24576       // ushorts: A [0,16384), B [16384,24576)

#define MM(D,A,B) D = __builtin_amdgcn_mfma_f32_16x16x32_bf16(A, B, D, 0, 0, 0)
#define GLD(SRC, DST) __builtin_amdgcn_global_load_lds( \
    (const __attribute__((address_space(1))) void*)(SRC), \
    (__attribute__((address_space(3))) void*)(DST), 16, 0, 0)
#define BAR() __builtin_amdgcn_s_barrier()
#define PRIO(x) __builtin_amdgcn_s_setprio(x)

__global__ __launch_bounds__(512, 2) void grouped_gemm(
    const unsigned short* __restrict__ xs,
    const float* __restrict__ W,
    const float* __restrict__ bias,
    const int* __restrict__ offs,
    const int* __restrict__ jobs,
    float* __restrict__ out) {
  __shared__ __align__(16) unsigned short sm[2 * SLOT];   // 96 KiB

  const int t    = threadIdx.x;
  const int lane = t & 63;
  const int wid  = t >> 6;
  const int wr   = wid >> 1;   // 0..3  (M quarter)
  const int wc   = wid & 1;    // 0..1  (N half)
  const int l15  = lane & 15;
  const int l4   = lane >> 4;

  // Fragment LDS read offsets (ushort units; rows 64 ush = 128B, swizzled).
  const int cb0  = (l4 * 8) ^ ((l15 & 7) << 3);
  const int cb1  = cb0 ^ 32;
  const int arow = (wr * 64 + l15) * 64;           // + m*1024
  const int brow = 16384 + (wc * 64 + l15) * 64;   // + n*1024

  // A staging: thread t covers row r0=t>>3 of a 64-row chunk, 16B col t&7;
  // inverse swizzle pre-applied to global k index.
  const int r0  = t >> 3;
  const int keu = ((t & 7) * 8) ^ ((r0 & 7) << 3);
  const int dA  = t * 8;

  // B staging: thread t owns column h = t&127, k-rows dgrp*16..+16.
  const int h    = t & 127;
  const int dgrp = t >> 7;                          // 0..3
  const int bw0  = 16384 + h * 64 + ((dgrp * 16) ^ ((h & 7) << 3));
  const int bw1  = 16384 + h * 64 + ((dgrp * 16 + 8) ^ ((h & 7) << 3));

#define LDB(P, K0) do { unsigned bi_ = bB + (unsigned)(K0) * 2048u; \
    P##0  = W[bi_];            P##1  = W[bi_ + 2048u]; \
    P##2  = W[bi_ + 4096u];    P##3  = W[bi_ + 6144u]; \
    P##4  = W[bi_ + 8192u];    P##5  = W[bi_ + 10240u]; \
    P##6  = W[bi_ + 12288u];   P##7  = W[bi_ + 14336u]; \
    P##8  = W[bi_ + 16384u];   P##9  = W[bi_ + 18432u]; \
    P##10 = W[bi_ + 20480u];   P##11 = W[bi_ + 22528u]; \
    P##12 = W[bi_ + 24576u];   P##13 = W[bi_ + 26624u]; \
    P##14 = W[bi_ + 28672u];   P##15 = W[bi_ + 30720u]; } while (0)

#define CVW(P, NSBASE) do { short8 s0_, s1_; \
    s0_[0]=(short)f2bf(P##0);  s0_[1]=(short)f2bf(P##1); \
    s0_[2]=(short)f2bf(P##2);  s0_[3]=(short)f2bf(P##3); \
    s0_[4]=(short)f2bf(P##4);  s0_[5]=(short)f2bf(P##5); \
    s0_[6]=(short)f2bf(P##6);  s0_[7]=(short)f2bf(P##7); \
    s1_[0]=(short)f2bf(P##8);  s1_[1]=(short)f2bf(P##9); \
    s1_[2]=(short)f2bf(P##10); s1_[3]=(short)f2bf(P##11); \
    s1_[4]=(short)f2bf(P##12); s1_[5]=(short)f2bf(P##13); \
    s1_[6]=(short)f2bf(P##14); s1_[7]=(short)f2bf(P##15); \
    *(short8*)(sm + (NSBASE) + bw0) = s0_; \
    *(short8*)(sm + (NSBASE) + bw1) = s1_; } while (0)

#define ST_A(SBASE, KOFS) do { \
    GLD(xs + pa0 + (KOFS), sm + (SBASE) + 0 * 4096 + dA); \
    GLD(xs + pa1 + (KOFS), sm + (SBASE) + 1 * 4096 + dA); \
    GLD(xs + pa2 + (KOFS), sm + (SBASE) + 2 * 4096 + dA); \
    GLD(xs + pa3 + (KOFS), sm + (SBASE) + 3 * 4096 + dA); } while (0)

#define READF(SP, CB) \
    fa0 = *(const short8*)((SP) + arow + 0 * 1024 + (CB)); \
    fa1 = *(const short8*)((SP) + arow + 1 * 1024 + (CB)); \
    fa2 = *(const short8*)((SP) + arow + 2 * 1024 + (CB)); \
    fa3 = *(const short8*)((SP) + arow + 3 * 1024 + (CB)); \
    fb0 = *(const short8*)((SP) + brow + 0 * 1024 + (CB)); \
    fb1 = *(const short8*)((SP) + brow + 1 * 1024 + (CB)); \
    fb2 = *(const short8*)((SP) + brow + 2 * 1024 + (CB)); \
    fb3 = *(const short8*)((SP) + brow + 3 * 1024 + (CB));

#define MFMA16() \
    MM(acc[0][0],fa0,fb0); MM(acc[0][1],fa0,fb1); MM(acc[0][2],fa0,fb2); MM(acc[0][3],fa0,fb3); \
    MM(acc[1][0],fa1,fb0); MM(acc[1][1],fa1,fb1); MM(acc[1][2],fa1,fb2); MM(acc[1][3],fa1,fb3); \
    MM(acc[2][0],fa2,fb0); MM(acc[2][1],fa2,fb1); MM(acc[2][2],fa2,fb2); MM(acc[2][3],fa2,fb3); \
    MM(acc[3][0],fa3,fb0); MM(acc[3][1],fa3,fb1); MM(acc[3][2],fa3,fb2); MM(acc[3][3],fa3,fb3);

// One K-tile: phase0 {reads ksub0 | stage A(T+1) | load B(T+2)->LB | bar |
// MFMA}, phase1 {reads ksub1 | cvt+write B(T+1) from CB | bar | MFMA |
// counted waits | bar}.
#define ITER(T, LB, CB) { \
    const int T_ = (T); \
    const unsigned short* SP = sm + ((T_ & 1) ? SLOT : 0); \
    const int NS = (T_ & 1) ? 0 : SLOT; \
    READF(SP, cb0); \
    if (T_ < NKT - 1) ST_A(NS, (T_ + 1) * 64); \
    if (T_ < NKT - 2) LDB(LB, (T_ + 2) * 64); \
    __builtin_amdgcn_sched_barrier(0); \
    BAR(); PRIO(1); \
    MFMA16(); \
    PRIO(0); BAR(); \
    READF(SP, cb1); \
    if (T_ < NKT - 1) CVW(CB, NS); \
    BAR(); PRIO(1); \
    MFMA16(); \
    PRIO(0); \
    if (T_ < NKT - 2)       { asm volatile("s_waitcnt vmcnt(16) lgkmcnt(0)" ::: "memory"); } \
    else if (T_ == NKT - 2) { asm volatile("s_waitcnt vmcnt(0) lgkmcnt(0)" ::: "memory"); } \
    else                    { asm volatile("s_waitcnt lgkmcnt(0)" ::: "memory"); } \
    BAR(); \
  }

  const int total = jobs[0] * 16;

#pragma unroll 1
  for (int j = blockIdx.x; j < total; j += 256) {
    const int jm  = jobs[1 + (j >> 4)];
    const int e   = jm & 255;
    const int mt  = jm >> 8;
    const int nx  = j & 15;
    const int off = offs[e];
    const int cnt = offs[e + 1] - off;
    if (mt * 256 >= cnt) continue;   // defensive (compact list: shouldn't hit)
    const int aBase = off + mt * 256;
    const int n0  = nx * 128;

    // A staging source bases.
    unsigned int pa0, pa1, pa2, pa3;
    {
      int p;
      p = aBase + 0 * 64 + r0; if (p > N_TOK - 1) p = N_TOK - 1; pa0 = (unsigned)p * 2048 + keu;
      p = aBase + 1 * 64 + r0; if (p > N_TOK - 1) p = N_TOK - 1; pa1 = (unsigned)p * 2048 + keu;
      p = aBase + 2 * 64 + r0; if (p > N_TOK - 1) p = N_TOK - 1; pa2 = (unsigned)p * 2048 + keu;
      p = aBase + 3 * 64 + r0; if (p > N_TOK - 1) p = N_TOK - 1; pa3 = (unsigned)p * 2048 + keu;
    }
    // B staging source base (fp32 W element index).
    const unsigned int bB = (unsigned)e * 4194304u + (unsigned)(n0 + h)
                          + (unsigned)dgrp * 32768u;

    float brA0, brA1, brA2, brA3, brA4, brA5, brA6, brA7,
          brA8, brA9, brA10, brA11, brA12, brA13, brA14, brA15;
    float brB0, brB1, brB2, brB3, brB4, brB5, brB6, brB7,
          brB8, brB9, brB10, brB11, brB12, brB13, brB14, brB15;

    f32x4 acc[4][4] = {};

    // Prologue: A(0)->slot0, B(0)->regs->slot0; B(1)->regs (bank brB).
    ST_A(0, 0);
    LDB(brA, 0);
    asm volatile("s_waitcnt vmcnt(0)" ::: "memory");
    CVW(brA, 0);
    LDB(brB, 64);
    asm volatile("s_waitcnt lgkmcnt(0)" ::: "memory");
    BAR();

    short8 fa0, fa1, fa2, fa3, fb0, fb1, fb2, fb3;

#pragma unroll 1
    for (int tt = 0; tt < NKT; tt += 2) {
      ITER(tt,     brA, brB);   // load B(tt+2)->brA, write B(tt+1) from brB
      ITER(tt + 1, brB, brA);
    }

    // Epilogue: bias + relu, masked tail rows.
#pragma unroll
    for (int n = 0; n < 4; ++n) {
      int col = n0 + wc * 64 + n * 16 + l15;
      float bv = bias[e * HID + col];
#pragma unroll
      for (int m = 0; m < 4; ++m) {
#pragma unroll
        for (int q = 0; q < 4; ++q) {
          int r = wr * 64 + m * 16 + l4 * 4 + q;
          if (mt * 256 + r < cnt) {
            float v = acc[m][n][q] + bv;
            out[(size_t)(off + mt * 256 + r) * HID + col] = v > 0.f ? v : 0.f;
          }
        }
      }
    }
  }
}

// ---------------------------------------------------------------------------
extern "C" void kernel_launch(void* const* d_in, const int* in_sizes, int n_in,
                              void* d_out, int out_size, void* d_ws, size_t ws_size,
                              hipStream_t stream) {
  const float* x   = (const float*)d_in[0];
  const int*   idx = (const int*)d_in[1];
  const float* W   = (const float*)d_in[2];
  const float* b   = (const float*)d_in[3];
  float* out = (float*)d_out;

  char* ws = (char*)d_ws;
  unsigned short* xs = (unsigned short*)ws;                 // 32 MB
  int* perm = (int*)(ws + (size_t)N_TOK * DIM * 2);
  int* offs = perm + N_TOK;
  int* jobs = offs + 16;

  sort_experts<<<1, 256, 0, stream>>>(idx, perm, offs, jobs);
  prep_x<<<N_TOK * (DIM / 8) / 256, 256, 0, stream>>>(x, perm, xs);
  grouped_gemm<<<256, 512, 0, stream>>>(xs, W, b, offs, jobs, out);
}